// Round 12
// baseline (173.561 us; speedup 1.0000x reference)
//
#include <hip/hip_runtime.h>
#include <cstdint>
#include <cstddef>

typedef __attribute__((ext_vector_type(8))) short short8;
typedef __attribute__((ext_vector_type(4))) float f32x4;

#define NROW 4096
#define NCOL 128
#define SPLIT 8
#define NM ((size_t)NROW * NCOL)

__device__ __forceinline__ unsigned short f2b(float f) {
  unsigned int u = __builtin_bit_cast(unsigned int, f);
  u += 0x7fffu + ((u >> 16) & 1u);   // round-to-nearest-even to bf16
  return (unsigned short)(u >> 16);
}
__device__ __forceinline__ float b2f(unsigned short b) {
  unsigned int u = ((unsigned int)b) << 16;
  return __builtin_bit_cast(float, u);
}

// ================= prep_all: one kernel for all independent prep work =================
__global__ __launch_bounds__(256) void prep_all(
    unsigned short* __restrict__ Thb, unsigned short* __restrict__ Ttb,
    const float* __restrict__ Th,
    unsigned short* __restrict__ fb, const float* __restrict__ features,
    unsigned short* __restrict__ W1bt, const float* __restrict__ W1,
    unsigned short* __restrict__ W2bt, const float* __restrict__ W2)
{
  __shared__ __align__(16) float shp[64 * 65];   // 16.6 KB
  const int j = blockIdx.x;
  const int t = threadIdx.x;
  if (j < 4096) {
    const int r0 = (j & 63) * 64, c0 = (j >> 6) * 64;
    const int c4 = (t & 15) * 4;
#pragma unroll
    for (int it = 0; it < 4; ++it) {
      int r = (t >> 4) + it * 16;
      float4 v = *(const float4*)(Th + (size_t)(r0 + r) * 4096 + c0 + c4);
      ushort4 o; o.x = f2b(v.x); o.y = f2b(v.y); o.z = f2b(v.z); o.w = f2b(v.w);
      *(ushort4*)(Thb + (size_t)(r0 + r) * 4096 + c0 + c4) = o;
      shp[r * 65 + c4 + 0] = v.x; shp[r * 65 + c4 + 1] = v.y;
      shp[r * 65 + c4 + 2] = v.z; shp[r * 65 + c4 + 3] = v.w;
    }
    __syncthreads();
    const int r4 = (t & 15) * 4;
#pragma unroll
    for (int it = 0; it < 4; ++it) {
      int c = (t >> 4) + it * 16;
      ushort4 o;
      o.x = f2b(shp[(r4 + 0) * 65 + c]); o.y = f2b(shp[(r4 + 1) * 65 + c]);
      o.z = f2b(shp[(r4 + 2) * 65 + c]); o.w = f2b(shp[(r4 + 3) * 65 + c]);
      *(ushort4*)(Ttb + (size_t)(c0 + c) * 4096 + r0 + r4) = o;
    }
  } else if (j < 5120) {
    size_t i = ((size_t)(j - 4096) * 256 + t) * 8;
    float4 v0 = *(const float4*)(features + i);
    float4 v1 = *(const float4*)(features + i + 4);
    ushort4 o0, o1;
    o0.x = f2b(v0.x); o0.y = f2b(v0.y); o0.z = f2b(v0.z); o0.w = f2b(v0.w);
    o1.x = f2b(v1.x); o1.y = f2b(v1.y); o1.z = f2b(v1.z); o1.w = f2b(v1.w);
    *(ushort4*)(fb + i) = o0; *(ushort4*)(fb + i + 4) = o1;
  } else {
    const float* in; unsigned short* outT; int R, bx, by;
    if (j < 5184) { int jj = j - 5120; in = W1; outT = W1bt; R = 512; bx = jj & 15; by = jj >> 4; }
    else          { int jj = j - 5184; in = W2; outT = W2bt; R = 128; bx = jj & 3;  by = jj >> 2; }
    float* sh2 = shp;                          // [32][33] view
    const int r0 = bx * 32, c0 = by * 32;
    {
      int r = t >> 3, c4 = (t & 7) * 4;
      float4 v = *(const float4*)(in + (size_t)(r0 + r) * 128 + c0 + c4);
      sh2[r * 33 + c4 + 0] = v.x; sh2[r * 33 + c4 + 1] = v.y;
      sh2[r * 33 + c4 + 2] = v.z; sh2[r * 33 + c4 + 3] = v.w;
    }
    __syncthreads();
    {
      int c = t >> 3, j4 = (t & 7) * 4;
      ushort4 o;
      o.x = f2b(sh2[(j4 + 0) * 33 + c]); o.y = f2b(sh2[(j4 + 1) * 33 + c]);
      o.z = f2b(sh2[(j4 + 2) * 33 + c]); o.w = f2b(sh2[(j4 + 3) * 33 + c]);
      *(ushort4*)(outT + (size_t)(c0 + c) * R + r0 + j4) = o;
    }
  }
}

// ================= small GEMM (fw = x@W), reg-staged 64x64 core + LDS-coalesced epilogue
__global__ __launch_bounds__(256) void gemm_small(float* __restrict__ C,
    unsigned short* __restrict__ Ct,
    const unsigned short* __restrict__ A, const unsigned short* __restrict__ Bt, int K)
{
  __shared__ __align__(16) char smem[20608];   // staging As@0 8KB, Bs@8192 8KB; epi [64][68] f32
  unsigned short* As = (unsigned short*)smem;
  unsigned short* Bs = (unsigned short*)(smem + 8192);
  const int tid = threadIdx.x;
  const int lane = tid & 63;
  const int w = tid >> 6;
  const int wr = w >> 1, wc = w & 1;
  const int m0 = blockIdx.x * 64, n0 = blockIdx.y * 64;
  f32x4 acc00 = {}, acc01 = {}, acc10 = {}, acc11 = {};

  const int r_st = tid >> 3;
  const int cc = tid & 7;
  const unsigned short* Ap0 = A + (size_t)(m0 + r_st) * K + cc * 8;
  const unsigned short* Ap1 = A + (size_t)(m0 + r_st + 32) * K + cc * 8;
  const unsigned short* Bp0 = Bt + (size_t)(n0 + r_st) * K + cc * 8;
  const unsigned short* Bp1 = Bt + (size_t)(n0 + r_st + 32) * K + cc * 8;
  const int wb0 = r_st * 128 + ((cc * 16) ^ ((r_st & 7) << 4));
  const int wb1 = wb0 + 32 * 128;
  char* AsB = (char*)As;
  char* BsB = (char*)Bs;
  const int krow = lane & 15, kgrp = lane >> 4;
  const int r0L = wr * 32 + krow;
  const int c0L = wc * 32 + krow;
  const int sw_r = (r0L & 7) << 4;
  const int sw_c = (c0L & 7) << 4;

  for (int k0 = 0; k0 < K; k0 += 64) {
    short8 a0 = *(const short8*)(const void*)(Ap0 + k0);
    short8 a1 = *(const short8*)(const void*)(Ap1 + k0);
    short8 b0 = *(const short8*)(const void*)(Bp0 + k0);
    short8 b1 = *(const short8*)(const void*)(Bp1 + k0);
    __syncthreads();
    *(short8*)(AsB + wb0) = a0;
    *(short8*)(AsB + wb1) = a1;
    *(short8*)(BsB + wb0) = b0;
    *(short8*)(BsB + wb1) = b1;
    __syncthreads();
#pragma unroll
    for (int kk = 0; kk < 64; kk += 32) {
      const int kb = (kk + 8 * kgrp) * 2;
      short8 af0 = *(const short8*)(AsB + r0L * 128 + (kb ^ sw_r));
      short8 af1 = *(const short8*)(AsB + (r0L + 16) * 128 + (kb ^ sw_r));
      short8 bf0 = *(const short8*)(BsB + c0L * 128 + (kb ^ sw_c));
      short8 bf1 = *(const short8*)(BsB + (c0L + 16) * 128 + (kb ^ sw_c));
      acc00 = __builtin_amdgcn_mfma_f32_16x16x32_bf16(af0, bf0, acc00, 0, 0, 0);
      acc01 = __builtin_amdgcn_mfma_f32_16x16x32_bf16(af0, bf1, acc01, 0, 0, 0);
      acc10 = __builtin_amdgcn_mfma_f32_16x16x32_bf16(af1, bf0, acc10, 0, 0, 0);
      acc11 = __builtin_amdgcn_mfma_f32_16x16x32_bf16(af1, bf1, acc11, 0, 0, 0);
    }
  }
  // ---- epilogue: stage 64x64 f32 tile in LDS, write coalesced
  __syncthreads();
  float* cs = (float*)smem;                    // [64][68]
  const int tr = wr * 32 + kgrp * 4, tc = wc * 32 + krow;
#pragma unroll
  for (int reg = 0; reg < 4; ++reg) {
    cs[(tr + reg) * 68 + tc]           = acc00[reg];
    cs[(tr + reg) * 68 + tc + 16]      = acc01[reg];
    cs[(tr + 16 + reg) * 68 + tc]      = acc10[reg];
    cs[(tr + 16 + reg) * 68 + tc + 16] = acc11[reg];
  }
  __syncthreads();
  // C f32 row-major (two passes of 32 rows; 8 lanes x 16B = full lines)
#pragma unroll
  for (int p = 0; p < 2; ++p) {
    const int r = p * 32 + (tid >> 3);
    const int c0 = (tid & 7) * 8;
    float4 v0 = *(float4*)(cs + r * 68 + c0);
    float4 v1 = *(float4*)(cs + r * 68 + c0 + 4);
    *(float4*)(C + (size_t)(m0 + r) * 128 + n0 + c0)     = v0;
    *(float4*)(C + (size_t)(m0 + r) * 128 + n0 + c0 + 4) = v1;
  }
  // Ct bf16 transposed: thread owns one col, 16 consecutive rows -> 32B contiguous
  {
    const int c = tid >> 2, r0w = (tid & 3) * 16;
    short8 o0, o1;
#pragma unroll
    for (int jj = 0; jj < 8; ++jj) {
      o0[jj] = (short)f2b(cs[(r0w + jj) * 68 + c]);
      o1[jj] = (short)f2b(cs[(r0w + 8 + jj) * 68 + c]);
    }
    *(short8*)(Ct + (size_t)(n0 + c) * NROW + m0 + r0w)     = o0;
    *(short8*)(Ct + (size_t)(n0 + c) * NROW + m0 + r0w + 8) = o1;
  }
}

// ================= split-K GEMM (r7 structure) + LDS-coalesced partial write ==========
// BM=32 x BN=128, BK=64, grid (128,1,SPLIT)=1024 blocks. gload_lds dwordx4 staging,
// pre-swizzled source, linear LDS dest, dbuf; sync -> issue next tile -> compute.
__global__ __launch_bounds__(256) void gemm_sk(unsigned short* __restrict__ P,
    const unsigned short* __restrict__ A, const unsigned short* __restrict__ Bt,
    int K, int KS)
{
  __shared__ __align__(16) unsigned short As[2][32 * 64];    // 2 x 4 KB
  __shared__ __align__(16) unsigned short Bs[2][128 * 64];   // 2 x 16 KB (epi: [32][132] f32)
  const int tid = threadIdx.x;
  const int lane = tid & 63;
  const int w = tid >> 6;
  const int wr = w >> 1, wc = w & 1;
  const int m0 = blockIdx.x * 32;
  const int s = blockIdx.z;
  const int kbeg = s * KS;
  const int NT = KS / 64;

  const int lrow = lane >> 3;                       // 0..7
  const int osw = (((lane & 7) ^ lrow) << 4);       // pre-swizzled byte offset in 128B row
  const unsigned char* Ab = (const unsigned char*)A;
  const unsigned char* Bb = (const unsigned char*)Bt;
  const size_t a_src = (size_t)(m0 + w * 8 + lrow) * ((size_t)K * 2) + osw + (size_t)kbeg * 2;
  size_t b_src[4];
#pragma unroll
  for (int j = 0; j < 4; ++j)                       // B rows: w*32 + j*8 + lrow (0..127)
    b_src[j] = (size_t)(w * 32 + j * 8 + lrow) * ((size_t)K * 2) + osw + (size_t)kbeg * 2;

  f32x4 acc[4] = {};
  const int krow = lane & 15, kgrp = lane >> 4;
  const int rA = wr * 16 + krow;
  const int rB = wc * 64 + krow;
  const int swz = (lane & 7) << 4;
  const int kb_base = kgrp * 16;

#define STAGE(b, tt) do {                                                            \
    const size_t ko_ = (size_t)(tt) * 128;                                           \
    __builtin_amdgcn_global_load_lds(                                                \
        (const __attribute__((address_space(1))) void*)(Ab + a_src + ko_),           \
        (__attribute__((address_space(3))) void*)((char*)As[b] + w * 1024),          \
        16, 0, 0);                                                                   \
    _Pragma("unroll")                                                                \
    for (int j3 = 0; j3 < 4; ++j3)                                                   \
      __builtin_amdgcn_global_load_lds(                                              \
          (const __attribute__((address_space(1))) void*)(Bb + b_src[j3] + ko_),     \
          (__attribute__((address_space(3))) void*)((char*)Bs[b] + (w * 4 + j3) * 1024), \
          16, 0, 0);                                                                 \
  } while (0)

  STAGE(0, 0);
  for (int t = 0; t < NT; ++t) {
    __syncthreads();                 // compiler drains vmcnt(0): tile t ready; prev reads done
    if (t + 1 < NT) STAGE((t + 1) & 1, t + 1);
    const char* la = (const char*)As[t & 1];
    const char* lb = (const char*)Bs[t & 1];
#pragma unroll
    for (int ks = 0; ks < 2; ++ks) {
      const int kb = ks * 64 + kb_base;
      short8 af  = *(const short8*)(la + rA * 128 + (kb ^ swz));
      short8 bf0 = *(const short8*)(lb + (rB)      * 128 + (kb ^ swz));
      short8 bf1 = *(const short8*)(lb + (rB + 16) * 128 + (kb ^ swz));
      short8 bf2 = *(const short8*)(lb + (rB + 32) * 128 + (kb ^ swz));
      short8 bf3 = *(const short8*)(lb + (rB + 48) * 128 + (kb ^ swz));
      acc[0] = __builtin_amdgcn_mfma_f32_16x16x32_bf16(af, bf0, acc[0], 0, 0, 0);
      acc[1] = __builtin_amdgcn_mfma_f32_16x16x32_bf16(af, bf1, acc[1], 0, 0, 0);
      acc[2] = __builtin_amdgcn_mfma_f32_16x16x32_bf16(af, bf2, acc[2], 0, 0, 0);
      acc[3] = __builtin_amdgcn_mfma_f32_16x16x32_bf16(af, bf3, acc[3], 0, 0, 0);
    }
  }
#undef STAGE

  // ---- epilogue: stage 32x128 f32 tile in LDS (reuse Bs), write full-line bf16 rows
  __syncthreads();                   // all waves done reading LDS
  float* cs = (float*)Bs;            // [32][132] f32 = 16.9 KB
  const int tr = wr * 16 + kgrp * 4;
  const int tc = wc * 64 + krow;
#pragma unroll
  for (int nf = 0; nf < 4; ++nf)
#pragma unroll
    for (int reg = 0; reg < 4; ++reg)
      cs[(tr + reg) * 132 + tc + nf * 16] = acc[nf][reg];
  __syncthreads();
  unsigned short* C = P + (size_t)s * NM;
  const int r = tid >> 3, c0 = (tid & 7) * 16;
  short8 o0, o1;
#pragma unroll
  for (int jj = 0; jj < 8; ++jj) {
    o0[jj] = (short)f2b(cs[r * 132 + c0 + jj]);
    o1[jj] = (short)f2b(cs[r * 132 + c0 + 8 + jj]);
  }
  *(short8*)(C + (size_t)(m0 + r) * 128 + c0)     = o0;
  *(short8*)(C + (size_t)(m0 + r) * 128 + c0 + 8) = o1;
}

// ================= reduce: sum SPLIT bf16 partials, optional combine, write f32 + bf16^T
template<int MODE>
__global__ __launch_bounds__(256) void reduce_tr(float* __restrict__ outF,
    unsigned short* __restrict__ outT, const unsigned short* __restrict__ P,
    const float* __restrict__ x1, const float* __restrict__ x2,
    const float* __restrict__ dv, const float* __restrict__ par)
{
  __shared__ float sh[32][33];
  const int r0 = blockIdx.x * 32, c0 = blockIdx.y * 32;
  const int t = threadIdx.x;
  const int r = t >> 3, c4 = (t & 7) * 4;
  const size_t base = (size_t)(r0 + r) * 128 + c0 + c4;

  float4 acc = {0.f, 0.f, 0.f, 0.f};
#pragma unroll
  for (int s = 0; s < SPLIT; ++s) {
    ushort4 v = *(const ushort4*)(P + (size_t)s * NM + base);
    acc.x += b2f(v.x); acc.y += b2f(v.y); acc.z += b2f(v.z); acc.w += b2f(v.w);
  }
  if (MODE == 1) {
    float d_ = dv[r0 + r];
    float p3 = par[3], p4 = par[4], p5 = par[5];
    float4 a = *(const float4*)(x1 + base);
    float4 b = *(const float4*)(x2 + base);
    acc.x = d_ * (p3 * a.x + p4 * b.x + p5 * acc.x);
    acc.y = d_ * (p3 * a.y + p4 * b.y + p5 * acc.y);
    acc.z = d_ * (p3 * a.z + p4 * b.z + p5 * acc.z);
    acc.w = d_ * (p3 * a.w + p4 * b.w + p5 * acc.w);
  }
  *(float4*)(outF + base) = acc;
  sh[r][c4 + 0] = acc.x; sh[r][c4 + 1] = acc.y; sh[r][c4 + 2] = acc.z; sh[r][c4 + 3] = acc.w;
  __syncthreads();
  const int c = t >> 3, j4 = (t & 7) * 4;
  ushort4 o;
  o.x = f2b(sh[j4 + 0][c]); o.y = f2b(sh[j4 + 1][c]);
  o.z = f2b(sh[j4 + 2][c]); o.w = f2b(sh[j4 + 3][c]);
  *(ushort4*)(outT + (size_t)(c0 + c) * NROW + r0 + j4) = o;
}

// h1 = relu(p0*y + p1*q1 + p2*sum(P)) -> bf16 row-major
__global__ __launch_bounds__(256) void reduce_h1(unsigned short* __restrict__ ho,
    const unsigned short* __restrict__ P, const float* __restrict__ y,
    const float* __restrict__ q1, const float* __restrict__ par)
{
  size_t i = ((size_t)blockIdx.x * 256 + threadIdx.x) * 4;
  float4 acc = {0.f, 0.f, 0.f, 0.f};
#pragma unroll
  for (int s = 0; s < SPLIT; ++s) {
    ushort4 v = *(const ushort4*)(P + (size_t)s * NM + i);
    acc.x += b2f(v.x); acc.y += b2f(v.y); acc.z += b2f(v.z); acc.w += b2f(v.w);
  }
  float p0 = par[0], p1 = par[1], p2 = par[2];
  float4 a = *(const float4*)(y + i), b = *(const float4*)(q1 + i);
  ushort4 o;
  o.x = f2b(fmaxf(p0 * a.x + p1 * b.x + p2 * acc.x, 0.f));
  o.y = f2b(fmaxf(p0 * a.y + p1 * b.y + p2 * acc.y, 0.f));
  o.z = f2b(fmaxf(p0 * a.z + p1 * b.z + p2 * acc.z, 0.f));
  o.w = f2b(fmaxf(p0 * a.w + p1 * b.w + p2 * acc.w, 0.f));
  *(ushort4*)(ho + i) = o;
}

// out = (ps0+ps1) * log_softmax(p0*y + p1*q1 + p2*sum(P), rows of 128) -> f32
__global__ __launch_bounds__(256) void final_sum(float* __restrict__ out,
    const unsigned short* __restrict__ P, const float* __restrict__ y,
    const float* __restrict__ q1, const float* __restrict__ par,
    const float* __restrict__ ps)
{
  int row = blockIdx.x * 4 + (threadIdx.x >> 6);
  int lane = threadIdx.x & 63;
  size_t i0 = (size_t)row * 128 + lane;
  size_t i1 = i0 + 64;
  float s0 = 0.f, s1 = 0.f;
#pragma unroll
  for (int s = 0; s < SPLIT; ++s) {
    s0 += b2f(P[(size_t)s * NM + i0]);
    s1 += b2f(P[(size_t)s * NM + i1]);
  }
  float p0 = par[0], p1 = par[1], p2 = par[2];
  float a0 = p0 * y[i0] + p1 * q1[i0] + p2 * s0;
  float a1 = p0 * y[i1] + p1 * q1[i1] + p2 * s1;
  float m = fmaxf(a0, a1);
#pragma unroll
  for (int off = 32; off; off >>= 1) m = fmaxf(m, __shfl_xor(m, off));
  float s = expf(a0 - m) + expf(a1 - m);
#pragma unroll
  for (int off = 32; off; off >>= 1) s += __shfl_xor(s, off);
  float ls = m + logf(s);
  float c = ps[0] + ps[1];
  out[i0] = c * (a0 - ls);
  out[i1] = c * (a1 - ls);
}

extern "C" void kernel_launch(void* const* d_in, const int* in_sizes, int n_in,
                              void* d_out, int out_size, void* d_ws, size_t ws_size,
                              hipStream_t stream) {
  (void)in_sizes; (void)n_in; (void)out_size; (void)ws_size;
  const float* features = (const float*)d_in[0];
  const float* Theta    = (const float*)d_in[1];
  const float* W1       = (const float*)d_in[2];
  const float* d1       = (const float*)d_in[3];
  const float* par1     = (const float*)d_in[4];
  const float* W2       = (const float*)d_in[5];
  const float* d2       = (const float*)d_in[6];
  const float* par2     = (const float*)d_in[7];
  const float* psnap    = (const float*)d_in[8];
  float* out            = (float*)d_out;

  char* w = (char*)d_ws;
  unsigned short* Thb  = (unsigned short*)w;  w += (size_t)4096 * 4096 * 2;
  unsigned short* Ttb  = (unsigned short*)w;  w += (size_t)4096 * 4096 * 2;
  unsigned short* fb   = (unsigned short*)w;  w += (size_t)4096 * 512 * 2;
  unsigned short* W1bt = (unsigned short*)w;  w += (size_t)128 * 512 * 2;
  unsigned short* W2bt = (unsigned short*)w;  w += (size_t)128 * 128 * 2;
  unsigned short* fwbt = (unsigned short*)w;  w += (size_t)128 * 4096 * 2;
  unsigned short* t1bt = (unsigned short*)w;  w += (size_t)128 * 4096 * 2;
  unsigned short* ybt  = (unsigned short*)w;  w += (size_t)128 * 4096 * 2;
  unsigned short* p1bt = (unsigned short*)w;  w += (size_t)128 * 4096 * 2;
  unsigned short* h1b  = (unsigned short*)w;  w += (size_t)4096 * 128 * 2;
  float* fwf = (float*)w;                     w += (size_t)4096 * 128 * 4;
  float* t1f = (float*)w;                     w += (size_t)4096 * 128 * 4;
  float* yf  = (float*)w;                     w += (size_t)4096 * 128 * 4;
  float* p1f = (float*)w;                     w += (size_t)4096 * 128 * 4;
  unsigned short* Pp = (unsigned short*)w;    w += (size_t)SPLIT * 4096 * 128 * 2;

  prep_all<<<5200, 256, 0, stream>>>(Thb, Ttb, Theta, fb, features, W1bt, W1, W2bt, W2);

  const dim3 gg(64, 2);
  const dim3 gk(128, 1, SPLIT);    // 1024 blocks
  const dim3 rg(128, 4);

  // ---- layer 1
  gemm_small<<<gg, 256, 0, stream>>>(fwf, fwbt, fb, W1bt, 512);
  gemm_sk<<<gk, 256, 0, stream>>>(Pp, Ttb, fwbt, 4096, 512);
  reduce_tr<0><<<rg, 256, 0, stream>>>(t1f, t1bt, Pp, nullptr, nullptr, nullptr, nullptr);
  gemm_sk<<<gk, 256, 0, stream>>>(Pp, Ttb, t1bt, 4096, 512);
  reduce_tr<1><<<rg, 256, 0, stream>>>(yf, ybt, Pp, fwf, t1f, d1, par1);
  gemm_sk<<<gk, 256, 0, stream>>>(Pp, Thb, ybt, 4096, 512);
  reduce_tr<0><<<rg, 256, 0, stream>>>(p1f, p1bt, Pp, nullptr, nullptr, nullptr, nullptr);
  gemm_sk<<<gk, 256, 0, stream>>>(Pp, Thb, p1bt, 4096, 512);
  reduce_h1<<<512, 256, 0, stream>>>(h1b, Pp, yf, p1f, par1);

  // ---- layer 2
  gemm_small<<<gg, 256, 0, stream>>>(fwf, fwbt, h1b, W2bt, 128);
  gemm_sk<<<gk, 256, 0, stream>>>(Pp, Ttb, fwbt, 4096, 512);
  reduce_tr<0><<<rg, 256, 0, stream>>>(t1f, t1bt, Pp, nullptr, nullptr, nullptr, nullptr);
  gemm_sk<<<gk, 256, 0, stream>>>(Pp, Ttb, t1bt, 4096, 512);
  reduce_tr<1><<<rg, 256, 0, stream>>>(yf, ybt, Pp, fwf, t1f, d2, par2);
  gemm_sk<<<gk, 256, 0, stream>>>(Pp, Thb, ybt, 4096, 512);
  reduce_tr<0><<<rg, 256, 0, stream>>>(p1f, p1bt, Pp, nullptr, nullptr, nullptr, nullptr);
  gemm_sk<<<gk, 256, 0, stream>>>(Pp, Thb, p1bt, 4096, 512);
  final_sum<<<1024, 256, 0, stream>>>(out, Pp, yf, p1f, par2, psnap);
}

// Round 13
// 169.561 us; speedup vs baseline: 1.0236x; 1.0236x over previous
//
#include <hip/hip_runtime.h>
#include <cstdint>
#include <cstddef>

typedef __attribute__((ext_vector_type(8))) short short8;
typedef __attribute__((ext_vector_type(4))) float f32x4;

#define NROW 4096
#define NCOL 128
#define SPLIT 8
#define NM ((size_t)NROW * NCOL)

__device__ __forceinline__ unsigned short f2b(float f) {
  unsigned int u = __builtin_bit_cast(unsigned int, f);
  u += 0x7fffu + ((u >> 16) & 1u);   // round-to-nearest-even to bf16
  return (unsigned short)(u >> 16);
}
__device__ __forceinline__ float b2f(unsigned short b) {
  unsigned int u = ((unsigned int)b) << 16;
  return __builtin_bit_cast(float, u);
}

// ================= prep_all: one kernel for all independent prep work =================
__global__ __launch_bounds__(256) void prep_all(
    unsigned short* __restrict__ Thb, unsigned short* __restrict__ Ttb,
    const float* __restrict__ Th,
    unsigned short* __restrict__ fb, const float* __restrict__ features,
    unsigned short* __restrict__ W1bt, const float* __restrict__ W1,
    unsigned short* __restrict__ W2bt, const float* __restrict__ W2)
{
  __shared__ __align__(16) float shp[64 * 65];   // 16.6 KB
  const int j = blockIdx.x;
  const int t = threadIdx.x;
  if (j < 4096) {
    const int r0 = (j & 63) * 64, c0 = (j >> 6) * 64;
    const int c4 = (t & 15) * 4;
#pragma unroll
    for (int it = 0; it < 4; ++it) {
      int r = (t >> 4) + it * 16;
      float4 v = *(const float4*)(Th + (size_t)(r0 + r) * 4096 + c0 + c4);
      ushort4 o; o.x = f2b(v.x); o.y = f2b(v.y); o.z = f2b(v.z); o.w = f2b(v.w);
      *(ushort4*)(Thb + (size_t)(r0 + r) * 4096 + c0 + c4) = o;
      shp[r * 65 + c4 + 0] = v.x; shp[r * 65 + c4 + 1] = v.y;
      shp[r * 65 + c4 + 2] = v.z; shp[r * 65 + c4 + 3] = v.w;
    }
    __syncthreads();
    const int r4 = (t & 15) * 4;
#pragma unroll
    for (int it = 0; it < 4; ++it) {
      int c = (t >> 4) + it * 16;
      ushort4 o;
      o.x = f2b(shp[(r4 + 0) * 65 + c]); o.y = f2b(shp[(r4 + 1) * 65 + c]);
      o.z = f2b(shp[(r4 + 2) * 65 + c]); o.w = f2b(shp[(r4 + 3) * 65 + c]);
      *(ushort4*)(Ttb + (size_t)(c0 + c) * 4096 + r0 + r4) = o;
    }
  } else if (j < 5120) {
    size_t i = ((size_t)(j - 4096) * 256 + t) * 8;
    float4 v0 = *(const float4*)(features + i);
    float4 v1 = *(const float4*)(features + i + 4);
    ushort4 o0, o1;
    o0.x = f2b(v0.x); o0.y = f2b(v0.y); o0.z = f2b(v0.z); o0.w = f2b(v0.w);
    o1.x = f2b(v1.x); o1.y = f2b(v1.y); o1.z = f2b(v1.z); o1.w = f2b(v1.w);
    *(ushort4*)(fb + i) = o0; *(ushort4*)(fb + i + 4) = o1;
  } else {
    const float* in; unsigned short* outT; int R, bx, by;
    if (j < 5184) { int jj = j - 5120; in = W1; outT = W1bt; R = 512; bx = jj & 15; by = jj >> 4; }
    else          { int jj = j - 5184; in = W2; outT = W2bt; R = 128; bx = jj & 3;  by = jj >> 2; }
    float* sh2 = shp;                          // [32][33] view
    const int r0 = bx * 32, c0 = by * 32;
    {
      int r = t >> 3, c4 = (t & 7) * 4;
      float4 v = *(const float4*)(in + (size_t)(r0 + r) * 128 + c0 + c4);
      sh2[r * 33 + c4 + 0] = v.x; sh2[r * 33 + c4 + 1] = v.y;
      sh2[r * 33 + c4 + 2] = v.z; sh2[r * 33 + c4 + 3] = v.w;
    }
    __syncthreads();
    {
      int c = t >> 3, j4 = (t & 7) * 4;
      ushort4 o;
      o.x = f2b(sh2[(j4 + 0) * 33 + c]); o.y = f2b(sh2[(j4 + 1) * 33 + c]);
      o.z = f2b(sh2[(j4 + 2) * 33 + c]); o.w = f2b(sh2[(j4 + 3) * 33 + c]);
      *(ushort4*)(outT + (size_t)(c0 + c) * R + r0 + j4) = o;
    }
  }
}

// ================= small GEMM #1 (fw = feat@W1), r7 body, bf16 outputs ====
__global__ __launch_bounds__(256) void gemm_small(unsigned short* __restrict__ Cb,
    unsigned short* __restrict__ Ct,
    const unsigned short* __restrict__ A, const unsigned short* __restrict__ Bt, int K)
{
  __shared__ __align__(16) unsigned short As[64 * 64];
  __shared__ __align__(16) unsigned short Bs[64 * 64];
  const int tid = threadIdx.x;
  const int lane = tid & 63;
  const int w = tid >> 6;
  const int wr = w >> 1, wc = w & 1;
  const int m0 = blockIdx.x * 64, n0 = blockIdx.y * 64;
  f32x4 acc00 = {}, acc01 = {}, acc10 = {}, acc11 = {};

  const int r_st = tid >> 3;
  const int cc = tid & 7;
  const unsigned short* Ap0 = A + (size_t)(m0 + r_st) * K + cc * 8;
  const unsigned short* Ap1 = A + (size_t)(m0 + r_st + 32) * K + cc * 8;
  const unsigned short* Bp0 = Bt + (size_t)(n0 + r_st) * K + cc * 8;
  const unsigned short* Bp1 = Bt + (size_t)(n0 + r_st + 32) * K + cc * 8;
  const int wb0 = r_st * 128 + ((cc * 16) ^ ((r_st & 7) << 4));
  const int wb1 = wb0 + 32 * 128;
  char* AsB = (char*)As;
  char* BsB = (char*)Bs;
  const int krow = lane & 15, kgrp = lane >> 4;
  const int r0L = wr * 32 + krow;
  const int c0L = wc * 32 + krow;
  const int sw_r = (r0L & 7) << 4;
  const int sw_c = (c0L & 7) << 4;

  for (int k0 = 0; k0 < K; k0 += 64) {
    short8 a0 = *(const short8*)(const void*)(Ap0 + k0);
    short8 a1 = *(const short8*)(const void*)(Ap1 + k0);
    short8 b0 = *(const short8*)(const void*)(Bp0 + k0);
    short8 b1 = *(const short8*)(const void*)(Bp1 + k0);
    __syncthreads();
    *(short8*)(AsB + wb0) = a0;
    *(short8*)(AsB + wb1) = a1;
    *(short8*)(BsB + wb0) = b0;
    *(short8*)(BsB + wb1) = b1;
    __syncthreads();
#pragma unroll
    for (int kk = 0; kk < 64; kk += 32) {
      const int kb = (kk + 8 * kgrp) * 2;
      short8 af0 = *(const short8*)(AsB + r0L * 128 + (kb ^ sw_r));
      short8 af1 = *(const short8*)(AsB + (r0L + 16) * 128 + (kb ^ sw_r));
      short8 bf0 = *(const short8*)(BsB + c0L * 128 + (kb ^ sw_c));
      short8 bf1 = *(const short8*)(BsB + (c0L + 16) * 128 + (kb ^ sw_c));
      acc00 = __builtin_amdgcn_mfma_f32_16x16x32_bf16(af0, bf0, acc00, 0, 0, 0);
      acc01 = __builtin_amdgcn_mfma_f32_16x16x32_bf16(af0, bf1, acc01, 0, 0, 0);
      acc10 = __builtin_amdgcn_mfma_f32_16x16x32_bf16(af1, bf0, acc10, 0, 0, 0);
      acc11 = __builtin_amdgcn_mfma_f32_16x16x32_bf16(af1, bf1, acc11, 0, 0, 0);
    }
  }
  const int orow = m0 + wr * 32 + kgrp * 4;
  const int ocol = n0 + wc * 32 + krow;
#pragma unroll
  for (int reg = 0; reg < 4; ++reg) {
    Cb[(size_t)(orow + reg) * 128 + ocol]           = f2b(acc00[reg]);
    Cb[(size_t)(orow + reg) * 128 + ocol + 16]      = f2b(acc01[reg]);
    Cb[(size_t)(orow + 16 + reg) * 128 + ocol]      = f2b(acc10[reg]);
    Cb[(size_t)(orow + 16 + reg) * 128 + ocol + 16] = f2b(acc11[reg]);
  }
  ushort4 o;
  o.x = f2b(acc00[0]); o.y = f2b(acc00[1]); o.z = f2b(acc00[2]); o.w = f2b(acc00[3]);
  *(ushort4*)(Ct + (size_t)ocol * NROW + orow) = o;
  o.x = f2b(acc10[0]); o.y = f2b(acc10[1]); o.z = f2b(acc10[2]); o.w = f2b(acc10[3]);
  *(ushort4*)(Ct + (size_t)ocol * NROW + orow + 16) = o;
  o.x = f2b(acc01[0]); o.y = f2b(acc01[1]); o.z = f2b(acc01[2]); o.w = f2b(acc01[3]);
  *(ushort4*)(Ct + (size_t)(ocol + 16) * NROW + orow) = o;
  o.x = f2b(acc11[0]); o.y = f2b(acc11[1]); o.z = f2b(acc11[2]); o.w = f2b(acc11[3]);
  *(ushort4*)(Ct + (size_t)(ocol + 16) * NROW + orow + 16) = o;
}

// ================= split-K GEMM (r7-exact body: best-measured baseline) ==========
__global__ __launch_bounds__(256) void gemm_sk(unsigned short* __restrict__ P,
    const unsigned short* __restrict__ A, const unsigned short* __restrict__ Bt,
    int K, int KS)
{
  __shared__ __align__(16) unsigned short As[2][32 * 64];    // 2 x 4 KB
  __shared__ __align__(16) unsigned short Bs[2][128 * 64];   // 2 x 16 KB
  const int tid = threadIdx.x;
  const int lane = tid & 63;
  const int w = tid >> 6;
  const int wr = w >> 1, wc = w & 1;
  const int m0 = blockIdx.x * 32;
  const int s = blockIdx.z;
  const int kbeg = s * KS;
  const int NT = KS / 64;

  const int lrow = lane >> 3;
  const int osw = (((lane & 7) ^ lrow) << 4);
  const unsigned char* Ab = (const unsigned char*)A;
  const unsigned char* Bb = (const unsigned char*)Bt;
  const size_t a_src = (size_t)(m0 + w * 8 + lrow) * ((size_t)K * 2) + osw + (size_t)kbeg * 2;
  size_t b_src[4];
#pragma unroll
  for (int j = 0; j < 4; ++j)
    b_src[j] = (size_t)(w * 32 + j * 8 + lrow) * ((size_t)K * 2) + osw + (size_t)kbeg * 2;

  f32x4 acc[4] = {};
  const int krow = lane & 15, kgrp = lane >> 4;
  const int rA = wr * 16 + krow;
  const int rB = wc * 64 + krow;
  const int swz = (lane & 7) << 4;
  const int kb_base = kgrp * 16;

#define STAGE(b, tt) do {                                                            \
    const size_t ko_ = (size_t)(tt) * 128;                                           \
    __builtin_amdgcn_global_load_lds(                                                \
        (const __attribute__((address_space(1))) void*)(Ab + a_src + ko_),           \
        (__attribute__((address_space(3))) void*)((char*)As[b] + w * 1024),          \
        16, 0, 0);                                                                   \
    _Pragma("unroll")                                                                \
    for (int j3 = 0; j3 < 4; ++j3)                                                   \
      __builtin_amdgcn_global_load_lds(                                              \
          (const __attribute__((address_space(1))) void*)(Bb + b_src[j3] + ko_),     \
          (__attribute__((address_space(3))) void*)((char*)Bs[b] + (w * 4 + j3) * 1024), \
          16, 0, 0);                                                                 \
  } while (0)

  STAGE(0, 0);
  for (int t = 0; t < NT; ++t) {
    __syncthreads();
    if (t + 1 < NT) STAGE((t + 1) & 1, t + 1);
    const char* la = (const char*)As[t & 1];
    const char* lb = (const char*)Bs[t & 1];
#pragma unroll
    for (int ks = 0; ks < 2; ++ks) {
      const int kb = ks * 64 + kb_base;
      short8 af  = *(const short8*)(la + rA * 128 + (kb ^ swz));
      short8 bf0 = *(const short8*)(lb + (rB)      * 128 + (kb ^ swz));
      short8 bf1 = *(const short8*)(lb + (rB + 16) * 128 + (kb ^ swz));
      short8 bf2 = *(const short8*)(lb + (rB + 32) * 128 + (kb ^ swz));
      short8 bf3 = *(const short8*)(lb + (rB + 48) * 128 + (kb ^ swz));
      acc[0] = __builtin_amdgcn_mfma_f32_16x16x32_bf16(af, bf0, acc[0], 0, 0, 0);
      acc[1] = __builtin_amdgcn_mfma_f32_16x16x32_bf16(af, bf1, acc[1], 0, 0, 0);
      acc[2] = __builtin_amdgcn_mfma_f32_16x16x32_bf16(af, bf2, acc[2], 0, 0, 0);
      acc[3] = __builtin_amdgcn_mfma_f32_16x16x32_bf16(af, bf3, acc[3], 0, 0, 0);
    }
  }
#undef STAGE

  unsigned short* C = P + (size_t)s * NM;
  const int orow = m0 + wr * 16 + kgrp * 4;
  const int ocol = wc * 64 + krow;
#pragma unroll
  for (int nf = 0; nf < 4; ++nf)
#pragma unroll
    for (int reg = 0; reg < 4; ++reg)
      C[(size_t)(orow + reg) * 128 + ocol + nf * 16] = f2b(acc[nf][reg]);
}

// ================= reduce: sum SPLIT bf16 partials, optional combine -> bf16 rm + bf16^T
template<int MODE>
__global__ __launch_bounds__(256) void reduce_tr(unsigned short* __restrict__ outB,
    unsigned short* __restrict__ outT, const unsigned short* __restrict__ P,
    const unsigned short* __restrict__ x1, const unsigned short* __restrict__ x2,
    const float* __restrict__ dv, const float* __restrict__ par)
{
  __shared__ float sh[32][33];
  const int r0 = blockIdx.x * 32, c0 = blockIdx.y * 32;
  const int t = threadIdx.x;
  const int r = t >> 3, c4 = (t & 7) * 4;
  const size_t base = (size_t)(r0 + r) * 128 + c0 + c4;

  float acc[4] = {0.f, 0.f, 0.f, 0.f};
#pragma unroll
  for (int s = 0; s < SPLIT; ++s) {
    ushort4 v = *(const ushort4*)(P + (size_t)s * NM + base);
    acc[0] += b2f(v.x); acc[1] += b2f(v.y); acc[2] += b2f(v.z); acc[3] += b2f(v.w);
  }
  if (MODE == 1) {
    float d_ = dv[r0 + r];
    float p3 = par[3], p4 = par[4], p5 = par[5];
    ushort4 a = *(const ushort4*)(x1 + base);
    ushort4 b = *(const ushort4*)(x2 + base);
    acc[0] = d_ * (p3 * b2f(a.x) + p4 * b2f(b.x) + p5 * acc[0]);
    acc[1] = d_ * (p3 * b2f(a.y) + p4 * b2f(b.y) + p5 * acc[1]);
    acc[2] = d_ * (p3 * b2f(a.z) + p4 * b2f(b.z) + p5 * acc[2]);
    acc[3] = d_ * (p3 * b2f(a.w) + p4 * b2f(b.w) + p5 * acc[3]);
  }
  ushort4 ob;
  ob.x = f2b(acc[0]); ob.y = f2b(acc[1]); ob.z = f2b(acc[2]); ob.w = f2b(acc[3]);
  *(ushort4*)(outB + base) = ob;
  sh[r][c4 + 0] = acc[0]; sh[r][c4 + 1] = acc[1]; sh[r][c4 + 2] = acc[2]; sh[r][c4 + 3] = acc[3];
  __syncthreads();
  const int c = t >> 3, j4 = (t & 7) * 4;
  ushort4 o;
  o.x = f2b(sh[j4 + 0][c]); o.y = f2b(sh[j4 + 1][c]);
  o.z = f2b(sh[j4 + 2][c]); o.w = f2b(sh[j4 + 3][c]);
  *(ushort4*)(outT + (size_t)(c0 + c) * NROW + r0 + j4) = o;
}

// ================= reduce_h1_mm: h1 = relu(combine) then fw = h1 @ W2 (fused, row-local K=128)
// 64 blocks x 256 thr; block owns 64 rows. Outputs fwb (bf16 rm) + fwbt (bf16 [128][4096]).
__global__ __launch_bounds__(256) void reduce_h1_mm(
    unsigned short* __restrict__ fwb, unsigned short* __restrict__ fwbt,
    const unsigned short* __restrict__ P, const unsigned short* __restrict__ yb,
    const unsigned short* __restrict__ q1, const float* __restrict__ par,
    const unsigned short* __restrict__ W2bt)
{
  __shared__ __align__(16) unsigned short h1s[64 * 136];   // 17.4 KB: h1 tile, later fw tile
  __shared__ __align__(16) unsigned short w2s[128 * 136];  // 34.8 KB: W2bt tile
  const int tid = threadIdx.x;
  const int lane = tid & 63;
  const int w = tid >> 6;
  const int m0 = blockIdx.x * 64;
  const float p0 = par[0], p1 = par[1], p2 = par[2];

  // phase A: h1 tile (64x128 bf16) into LDS
#pragma unroll
  for (int p = 0; p < 2; ++p) {
    const int r = p * 32 + (tid >> 3);
    const int c0 = (tid & 7) * 16;
    const size_t base = (size_t)(m0 + r) * 128 + c0;
    float v[16];
#pragma unroll
    for (int q = 0; q < 16; ++q) v[q] = 0.f;
#pragma unroll
    for (int s = 0; s < SPLIT; ++s) {
      const unsigned short* Ps = P + (size_t)s * NM + base;
#pragma unroll
      for (int q = 0; q < 4; ++q) {
        ushort4 u = *(const ushort4*)(Ps + q * 4);
        v[q * 4 + 0] += b2f(u.x); v[q * 4 + 1] += b2f(u.y);
        v[q * 4 + 2] += b2f(u.z); v[q * 4 + 3] += b2f(u.w);
      }
    }
#pragma unroll
    for (int q = 0; q < 4; ++q) {
      ushort4 a = *(const ushort4*)(yb + base + q * 4);
      ushort4 b = *(const ushort4*)(q1 + base + q * 4);
      h1s[r * 136 + c0 + q * 4 + 0] = f2b(fmaxf(p0 * b2f(a.x) + p1 * b2f(b.x) + p2 * v[q * 4 + 0], 0.f));
      h1s[r * 136 + c0 + q * 4 + 1] = f2b(fmaxf(p0 * b2f(a.y) + p1 * b2f(b.y) + p2 * v[q * 4 + 1], 0.f));
      h1s[r * 136 + c0 + q * 4 + 2] = f2b(fmaxf(p0 * b2f(a.z) + p1 * b2f(b.z) + p2 * v[q * 4 + 2], 0.f));
      h1s[r * 136 + c0 + q * 4 + 3] = f2b(fmaxf(p0 * b2f(a.w) + p1 * b2f(b.w) + p2 * v[q * 4 + 3], 0.f));
    }
  }
  // stage W2bt [128][128] -> w2s [128][136]
  {
    const int rw = tid >> 1, half = (tid & 1) * 64;
#pragma unroll
    for (int q = 0; q < 8; ++q) {
      short8 vv = *(const short8*)(const void*)(W2bt + (size_t)rw * 128 + half + q * 8);
      *(short8*)(w2s + rw * 136 + half + q * 8) = vv;
    }
  }
  __syncthreads();

  // phase B: fw(64x128) = h1 @ W2 ; wave w owns rows w*16..+16 (Mw=16, Nw=128)
  f32x4 acc[8] = {};
  const int krow = lane & 15, kgrp = lane >> 4;
  const int arow = w * 16 + krow;
#pragma unroll
  for (int ks = 0; ks < 4; ++ks) {
    const int k0 = ks * 32 + kgrp * 8;
    short8 af = *(const short8*)(const void*)(h1s + arow * 136 + k0);
#pragma unroll
    for (int nf = 0; nf < 8; ++nf) {
      short8 bf = *(const short8*)(const void*)(w2s + (nf * 16 + krow) * 136 + k0);
      acc[nf] = __builtin_amdgcn_mfma_f32_16x16x32_bf16(af, bf, acc[nf], 0, 0, 0);
    }
  }
  __syncthreads();                       // all h1 reads done; reuse h1s for fw tile
#pragma unroll
  for (int nf = 0; nf < 8; ++nf)         // C/D: col = krow + nf*16, row = kgrp*4 + reg
#pragma unroll
    for (int reg = 0; reg < 4; ++reg)
      h1s[(w * 16 + kgrp * 4 + reg) * 136 + krow + nf * 16] = f2b(acc[nf][reg]);
  __syncthreads();
  {  // coalesced fwb row-major
    const int r = tid >> 2, c0 = (tid & 3) * 32;
#pragma unroll
    for (int q = 0; q < 4; ++q) {
      short8 vv = *(const short8*)(const void*)(h1s + r * 136 + c0 + q * 8);
      *(short8*)(fwb + (size_t)(m0 + r) * 128 + c0 + q * 8) = vv;
    }
  }
  {  // fwbt transposed
    const int c = tid >> 1, r0w = (tid & 1) * 32;
#pragma unroll
    for (int q = 0; q < 4; ++q) {
      short8 vv;
#pragma unroll
      for (int jj = 0; jj < 8; ++jj)
        vv[jj] = (short)h1s[(r0w + q * 8 + jj) * 136 + c];
      *(short8*)(fwbt + (size_t)c * NROW + m0 + r0w + q * 8) = vv;
    }
  }
}

// out = (ps0+ps1) * log_softmax(p0*y + p1*q1 + p2*sum(P), rows of 128) -> f32
__global__ __launch_bounds__(256) void final_sum(float* __restrict__ out,
    const unsigned short* __restrict__ P, const unsigned short* __restrict__ yb,
    const unsigned short* __restrict__ q1, const float* __restrict__ par,
    const float* __restrict__ ps)
{
  int row = blockIdx.x * 4 + (threadIdx.x >> 6);
  int lane = threadIdx.x & 63;
  size_t i0 = (size_t)row * 128 + lane;
  size_t i1 = i0 + 64;
  float s0 = 0.f, s1 = 0.f;
#pragma unroll
  for (int s = 0; s < SPLIT; ++s) {
    s0 += b2f(P[(size_t)s * NM + i0]);
    s1 += b2f(P[(size_t)s * NM + i1]);
  }
  float p0 = par[0], p1 = par[1], p2 = par[2];
  float a0 = p0 * b2f(yb[i0]) + p1 * b2f(q1[i0]) + p2 * s0;
  float a1 = p0 * b2f(yb[i1]) + p1 * b2f(q1[i1]) + p2 * s1;
  float m = fmaxf(a0, a1);
#pragma unroll
  for (int off = 32; off; off >>= 1) m = fmaxf(m, __shfl_xor(m, off));
  float s = expf(a0 - m) + expf(a1 - m);
#pragma unroll
  for (int off = 32; off; off >>= 1) s += __shfl_xor(s, off);
  float ls = m + logf(s);
  float c = ps[0] + ps[1];
  out[i0] = c * (a0 - ls);
  out[i1] = c * (a1 - ls);
}

extern "C" void kernel_launch(void* const* d_in, const int* in_sizes, int n_in,
                              void* d_out, int out_size, void* d_ws, size_t ws_size,
                              hipStream_t stream) {
  (void)in_sizes; (void)n_in; (void)out_size; (void)ws_size;
  const float* features = (const float*)d_in[0];
  const float* Theta    = (const float*)d_in[1];
  const float* W1       = (const float*)d_in[2];
  const float* d1       = (const float*)d_in[3];
  const float* par1     = (const float*)d_in[4];
  const float* W2       = (const float*)d_in[5];
  const float* d2       = (const float*)d_in[6];
  const float* par2     = (const float*)d_in[7];
  const float* psnap    = (const float*)d_in[8];
  float* out            = (float*)d_out;

  char* w = (char*)d_ws;
  unsigned short* Thb  = (unsigned short*)w;  w += (size_t)4096 * 4096 * 2;
  unsigned short* Ttb  = (unsigned short*)w;  w += (size_t)4096 * 4096 * 2;
  unsigned short* fb   = (unsigned short*)w;  w += (size_t)4096 * 512 * 2;
  unsigned short* W1bt = (unsigned short*)w;  w += (size_t)128 * 512 * 2;
  unsigned short* W2bt = (unsigned short*)w;  w += (size_t)128 * 128 * 2;
  unsigned short* fwbt = (unsigned short*)w;  w += (size_t)128 * 4096 * 2;
  unsigned short* t1bt = (unsigned short*)w;  w += (size_t)128 * 4096 * 2;
  unsigned short* ybt  = (unsigned short*)w;  w += (size_t)128 * 4096 * 2;
  unsigned short* p1bt = (unsigned short*)w;  w += (size_t)128 * 4096 * 2;
  unsigned short* fwb  = (unsigned short*)w;  w += (size_t)4096 * 128 * 2;
  unsigned short* t1b  = (unsigned short*)w;  w += (size_t)4096 * 128 * 2;
  unsigned short* yb   = (unsigned short*)w;  w += (size_t)4096 * 128 * 2;
  unsigned short* p1b  = (unsigned short*)w;  w += (size_t)4096 * 128 * 2;
  unsigned short* Pp   = (unsigned short*)w;  w += (size_t)SPLIT * 4096 * 128 * 2;

  prep_all<<<5200, 256, 0, stream>>>(Thb, Ttb, Theta, fb, features, W1bt, W1, W2bt, W2);

  const dim3 gg(64, 2);
  const dim3 gk(128, 1, SPLIT);    // 1024 blocks
  const dim3 rg(128, 4);

  // ---- layer 1
  gemm_small<<<gg, 256, 0, stream>>>(fwb, fwbt, fb, W1bt, 512);
  gemm_sk<<<gk, 256, 0, stream>>>(Pp, Ttb, fwbt, 4096, 512);
  reduce_tr<0><<<rg, 256, 0, stream>>>(t1b, t1bt, Pp, nullptr, nullptr, nullptr, nullptr);
  gemm_sk<<<gk, 256, 0, stream>>>(Pp, Ttb, t1bt, 4096, 512);
  reduce_tr<1><<<rg, 256, 0, stream>>>(yb, ybt, Pp, fwb, t1b, d1, par1);
  gemm_sk<<<gk, 256, 0, stream>>>(Pp, Thb, ybt, 4096, 512);
  reduce_tr<0><<<rg, 256, 0, stream>>>(p1b, p1bt, Pp, nullptr, nullptr, nullptr, nullptr);
  gemm_sk<<<gk, 256, 0, stream>>>(Pp, Thb, p1bt, 4096, 512);
  reduce_h1_mm<<<64, 256, 0, stream>>>(fwb, fwbt, Pp, yb, p1b, par1, W2bt);

  // ---- layer 2 (gemm_small #2 eliminated — fused above)
  gemm_sk<<<gk, 256, 0, stream>>>(Pp, Ttb, fwbt, 4096, 512);
  reduce_tr<0><<<rg, 256, 0, stream>>>(t1b, t1bt, Pp, nullptr, nullptr, nullptr, nullptr);
  gemm_sk<<<gk, 256, 0, stream>>>(Pp, Ttb, t1bt, 4096, 512);
  reduce_tr<1><<<rg, 256, 0, stream>>>(yb, ybt, Pp, fwb, t1b, d2, par2);
  gemm_sk<<<gk, 256, 0, stream>>>(Pp, Thb, ybt, 4096, 512);
  reduce_tr<0><<<rg, 256, 0, stream>>>(p1b, p1bt, Pp, nullptr, nullptr, nullptr, nullptr);
  gemm_sk<<<gk, 256, 0, stream>>>(Pp, Thb, p1bt, 4096, 512);
  final_sum<<<1024, 256, 0, stream>>>(out, Pp, yb, p1b, par2, psnap);
}